// Round 1
// 312.018 us; speedup vs baseline: 1.0517x; 1.0517x over previous
//
#include <hip/hip_runtime.h>
#include <math.h>

// Problem constants (SwinBlock: B=4, H=W=224, C=96, WS=8, shift=4, NH=3, hd=32)
static constexpr int Hn   = 224;
static constexpr int Wn   = 224;
static constexpr int Cn   = 96;
static constexpr int Sft  = 4;     // WS/2
static constexpr int NWH  = 28;    // 224/8
static constexpr int NWPB = 784;   // 28*28
static constexpr int NW   = 3136;  // 4*784

typedef __attribute__((ext_vector_type(8))) short bf16x8;  // 8 bf16 in 4 VGPRs
typedef __attribute__((ext_vector_type(4))) float f32x4;
typedef __attribute__((ext_vector_type(4))) short s16x4;

__device__ inline short f2bf(float f) {            // RNE float->bf16
    unsigned u = __float_as_uint(f);
    return (short)((u + 0x7fffu + ((u >> 16) & 1u)) >> 16);
}

// ---------------------------------------------------------------------------
// K0: convert ALL weights to bf16 into ws.
// layout (shorts): wqb[27648] | wob[9216] | w1b[36864] | w2b[36864]  (221184 B)
// All row-major [oc][k] -> K contiguous for B-fragments.
// ---------------------------------------------------------------------------
__global__ void prep_bf16(const float* __restrict__ wqkv, const float* __restrict__ wo,
                          const float* __restrict__ w1,   const float* __restrict__ w2,
                          short* __restrict__ ws) {
    int idx = blockIdx.x * 256 + threadIdx.x;
    if (idx < 27648)        ws[idx] = f2bf(wqkv[idx]);
    else if (idx < 36864)   ws[idx] = f2bf(wo[idx - 27648]);
    else if (idx < 73728)   ws[idx] = f2bf(w1[idx - 36864]);
    else if (idx < 110592)  ws[idx] = f2bf(w2[idx - 73728]);
}

// ---------------------------------------------------------------------------
// K1: MFMA attention. One block = one 8x8 window (64 tokens), 4 waves.
//  roll+partition (tbase trick) -> LN1 -> QKV MFMA (V stored transposed) ->
//  S=QK^T MFMA -> in-register softmax (16-lane butterfly) -> PV MFMA ->
//  out-proj MFMA -> fp32 stage -> coalesced write (un-roll cancels roll).
// Fragment layouts (mfma_f32_16x16x32_bf16, m89-verified):
//  A: row=lane&15, k=(lane>>4)*8+j ; B: col=lane&15, same k ;
//  D: col=lane&15, row=(lane>>4)*4+r
//
// R4 occupancy rework: ONE union buffer U[64][400B] time-shares
//   xf f32 (LN input) -> Q|K bf16 (stride 200 shorts) -> P bf16 -> st f32.
// Legality: xf dead after LN (no residual in attn path); Q,K dead after the
// S-MFMAs of ALL waves (new __syncthreads before P overwrites them); P dead
// per-wave after own PV reads (st overwrite is own-wave, program-ordered).
// Biases read straight from global (L2-hot) instead of an sbias LDS copy.
// LDS: 25600(U) + 13312(h2b) + 13824(vt) + 256(tbase) = 52992 B -> 3 blocks/CU
// (was 80128 -> 2 blocks/CU).
// ---------------------------------------------------------------------------
static constexpr int LDH  = 104;  // h2b / O stride (shorts)
static constexpr int LDQK = 200;  // U as Q|K: stride (shorts): Q[0..95] K[96..191] pad8
static constexpr int LDVT = 72;   // vt stride (shorts): [ch 96][tok 64 pad8]
static constexpr int LDP  = 200;  // U as P: [tok][h*64+kv] pad8 (shorts)
static constexpr int LDXF = 100;  // U as xf: stride (floats)
static constexpr int LDST = 100;  // U as st: stride (floats)

__global__ __launch_bounds__(256, 3) void attn_mfma(
    const float* __restrict__ x,
    const float* __restrict__ ln1w, const float* __restrict__ ln1b,
    const short* __restrict__ wqb,  const float* __restrict__ bqkv,
    const short* __restrict__ wob,  const float* __restrict__ bo,
    float* __restrict__ out)
{
    __shared__ __align__(16) char  U[64 * 400];        // xf -> Q|K -> P -> st
    __shared__ __align__(16) short h2b[64 * LDH];      // LN out bf16 -> O bf16
    __shared__ __align__(16) short vt[96 * LDVT];      // V^T [ch][tok]
    __shared__ int   tbase[64];

    const int blk = blockIdx.x;
    const int b   = blk / NWPB;
    const int rem = blk - b * NWPB;
    const int wh  = rem / NWH;
    const int ww  = rem - wh * NWH;
    const int tid  = threadIdx.x;
    const int lane = tid & 63;
    const int wv   = __builtin_amdgcn_readfirstlane(tid >> 6);
    const int lr   = lane & 15;
    const int lk   = lane >> 4;

    if (tid < 64) {
        int i = tid >> 3, j = tid & 7;
        int hs = wh * 8 + i + Sft; if (hs >= Hn) hs -= Hn;
        int ws2 = ww * 8 + j + Sft; if (ws2 >= Wn) ws2 -= Wn;
        tbase[tid] = ((b * Hn + hs) * Wn + ws2) * Cn;
    }
    __syncthreads();

    // ---- P1: load x [64][96] (float4, 16B-aligned rows) into U as xf ----
    float* xf = (float*)U;
    for (int i = tid; i < 64 * 24; i += 256) {
        int row = i / 24, c4 = i - row * 24;
        float4 v = ((const float4*)(x + tbase[row]))[c4];
        *(float4*)&xf[row * LDXF + c4 * 4] = v;
    }
    __syncthreads();

    // ---- P2: LN1 (4 lanes/token; wave wv covers exactly token tile wv) ----
    {
        const int l = tid >> 2, p = tid & 3;
        float s0 = 0.f, s1 = 0.f;
        #pragma unroll
        for (int c0 = 0; c0 < 24; ++c0) {
            float v = xf[l * LDXF + p * 24 + c0];
            s0 += v; s1 += v * v;
        }
        s0 += __shfl_xor(s0, 1); s1 += __shfl_xor(s1, 1);
        s0 += __shfl_xor(s0, 2); s1 += __shfl_xor(s1, 2);
        float mean = s0 * (1.f / 96.f);
        float var  = fmaxf(s1 * (1.f / 96.f) - mean * mean, 0.f);
        float rstd = rsqrtf(var + 1e-5f);
        #pragma unroll
        for (int c0 = 0; c0 < 24; ++c0) {
            int c = p * 24 + c0;
            float v = xf[l * LDXF + c];
            h2b[l * LDH + c] = f2bf((v - mean) * rstd * ln1w[c] + ln1b[c]);
        }
    }
    __syncthreads();   // h2b ready; also fences xf reads before Q/K overwrite

    // ---- P3: QKV GEMM. wave -> row-tile wv (16 tokens), 18 col-tiles of 16 ----
    // Q,K -> U (stride LDQK, own-wave rows); V -> vt transposed.
    short* qk = (short*)U;
    {
        bf16x8 a0 = *(const bf16x8*)&h2b[(wv * 16 + lr) * LDH +  0 + lk * 8];
        bf16x8 a1 = *(const bf16x8*)&h2b[(wv * 16 + lr) * LDH + 32 + lk * 8];
        bf16x8 a2 = *(const bf16x8*)&h2b[(wv * 16 + lr) * LDH + 64 + lk * 8];
        #pragma unroll 6
        for (int ct = 0; ct < 18; ++ct) {
            const short* bp = wqb + (ct * 16 + lr) * 96 + lk * 8;
            bf16x8 b0 = *(const bf16x8*)(bp);
            bf16x8 b1 = *(const bf16x8*)(bp + 32);
            bf16x8 b2 = *(const bf16x8*)(bp + 64);
            f32x4 acc = (f32x4){0.f, 0.f, 0.f, 0.f};
            acc = __builtin_amdgcn_mfma_f32_16x16x32_bf16(a0, b0, acc, 0, 0, 0);
            acc = __builtin_amdgcn_mfma_f32_16x16x32_bf16(a1, b1, acc, 0, 0, 0);
            acc = __builtin_amdgcn_mfma_f32_16x16x32_bf16(a2, b2, acc, 0, 0, 0);
            const int col  = ct * 16 + lr;
            const float bs = bqkv[col];                // L2-hot global
            if (ct < 12) {            // Q,K -> [tok][ch] in U
                #pragma unroll
                for (int r = 0; r < 4; ++r)
                    qk[(wv * 16 + lk * 4 + r) * LDQK + col] = f2bf(acc[r] + bs);
            } else {                  // V -> transposed [ch][tok], packed b64
                s16x4 pk;
                #pragma unroll
                for (int r = 0; r < 4; ++r) pk[r] = f2bf(acc[r] + bs);
                *(s16x4*)&vt[(col - 192) * LDVT + wv * 16 + lk * 4] = pk;
            }
        }
    }
    __syncthreads();   // Q,K,V visible to all waves

    // ---- P4: S = QK^T per head (wave -> query row-tile wv), softmax ----
    short* pb = (short*)U;   // P overwrites Q|K after the barrier below
    {
        f32x4 accs[3][4];
        #pragma unroll
        for (int h = 0; h < 3; ++h) {
            bf16x8 aq = *(const bf16x8*)&qk[(wv * 16 + lr) * LDQK + h * 32 + lk * 8];
            #pragma unroll
            for (int ct = 0; ct < 4; ++ct) {
                bf16x8 bk = *(const bf16x8*)&qk[(ct * 16 + lr) * LDQK + 96 + h * 32 + lk * 8];
                f32x4 z = (f32x4){0.f, 0.f, 0.f, 0.f};
                accs[h][ct] = __builtin_amdgcn_mfma_f32_16x16x32_bf16(aq, bk, z, 0, 0, 0);
            }
        }
        __syncthreads();   // NEW: every wave done reading K -> P may overwrite U

        const float scale = 0.17677669529663687f;  // 1/sqrt(32)
        float inv[3][4];
        #pragma unroll
        for (int h = 0; h < 3; ++h) {
            #pragma unroll
            for (int r = 0; r < 4; ++r) {
                float m = fmaxf(fmaxf(accs[h][0][r], accs[h][1][r]),
                                fmaxf(accs[h][2][r], accs[h][3][r]));
                m = fmaxf(m, __shfl_xor(m, 1));
                m = fmaxf(m, __shfl_xor(m, 2));
                m = fmaxf(m, __shfl_xor(m, 4));
                m = fmaxf(m, __shfl_xor(m, 8));
                float s = 0.f;
                #pragma unroll
                for (int ct = 0; ct < 4; ++ct) {
                    float p = __expf((accs[h][ct][r] - m) * scale);
                    accs[h][ct][r] = p; s += p;
                }
                s += __shfl_xor(s, 1); s += __shfl_xor(s, 2);
                s += __shfl_xor(s, 4); s += __shfl_xor(s, 8);
                inv[h][r] = 1.f / s;
            }
        }
        // P -> bf16 LDS (rows of own wave only; no barrier needed)
        #pragma unroll
        for (int h = 0; h < 3; ++h)
            #pragma unroll
            for (int ct = 0; ct < 4; ++ct)
                #pragma unroll
                for (int r = 0; r < 4; ++r)
                    pb[(wv * 16 + lk * 4 + r) * LDP + h * 64 + ct * 16 + lr] =
                        f2bf(accs[h][ct][r]);

        // ---- P5: O = P V (deferred 1/sum), write O bf16 into h2b ----
        f32x4 acco[3][2];
        #pragma unroll
        for (int h = 0; h < 3; ++h)
            #pragma unroll
            for (int ct = 0; ct < 2; ++ct) acco[h][ct] = (f32x4){0.f, 0.f, 0.f, 0.f};
        #pragma unroll
        for (int h = 0; h < 3; ++h) {
            #pragma unroll
            for (int ks = 0; ks < 2; ++ks) {
                bf16x8 ap = *(const bf16x8*)&pb[(wv * 16 + lr) * LDP + h * 64 + ks * 32 + lk * 8];
                #pragma unroll
                for (int ct = 0; ct < 2; ++ct) {
                    bf16x8 bv = *(const bf16x8*)&vt[(h * 32 + ct * 16 + lr) * LDVT + ks * 32 + lk * 8];
                    acco[h][ct] = __builtin_amdgcn_mfma_f32_16x16x32_bf16(ap, bv, acco[h][ct], 0, 0, 0);
                }
            }
        }
        #pragma unroll
        for (int h = 0; h < 3; ++h)
            #pragma unroll
            for (int ct = 0; ct < 2; ++ct)
                #pragma unroll
                for (int r = 0; r < 4; ++r)
                    h2b[(wv * 16 + lk * 4 + r) * LDH + h * 32 + ct * 16 + lr] =
                        f2bf(acco[h][ct][r] * inv[h][r]);
    }

    // ---- P6: out-proj (A = O rows of own wave; B = wob) ----
    {
        bf16x8 o0 = *(const bf16x8*)&h2b[(wv * 16 + lr) * LDH +  0 + lk * 8];
        bf16x8 o1 = *(const bf16x8*)&h2b[(wv * 16 + lr) * LDH + 32 + lk * 8];
        bf16x8 o2 = *(const bf16x8*)&h2b[(wv * 16 + lr) * LDH + 64 + lk * 8];
        float* st = (float*)U;   // overwrites pb: own-wave rows, program-ordered
        #pragma unroll
        for (int ct = 0; ct < 6; ++ct) {
            const short* bp = wob + (ct * 16 + lr) * 96 + lk * 8;
            bf16x8 b0 = *(const bf16x8*)(bp);
            bf16x8 b1 = *(const bf16x8*)(bp + 32);
            bf16x8 b2 = *(const bf16x8*)(bp + 64);
            f32x4 acc = (f32x4){0.f, 0.f, 0.f, 0.f};
            acc = __builtin_amdgcn_mfma_f32_16x16x32_bf16(o0, b0, acc, 0, 0, 0);
            acc = __builtin_amdgcn_mfma_f32_16x16x32_bf16(o1, b1, acc, 0, 0, 0);
            acc = __builtin_amdgcn_mfma_f32_16x16x32_bf16(o2, b2, acc, 0, 0, 0);
            const int col = ct * 16 + lr;
            const float bs = bo[col];                  // L2-hot global
            #pragma unroll
            for (int r = 0; r < 4; ++r)
                st[(wv * 16 + lk * 4 + r) * LDST + col] = acc[r] + bs;
        }
    }
    __syncthreads();

    // ---- P7: coalesced write-back; un-roll cancels the roll ----
    {
        const float* st = (const float*)U;
        for (int i = tid; i < 64 * 96; i += 256) {
            int l = i / 96, c = i - l * 96;
            out[tbase[l] + c] = st[l * LDST + c];
        }
    }
}

// ---------------------------------------------------------------------------
// K2: MFMA MLP.
// R4 occupancy rework: xf LDS buffer removed. LN2 runs from registers (each
// thread already owns one token-quarter = 24 contiguous floats); the residual
// re-reads xio in the epilogue (L2-hot; read-then-write by the SAME thread,
// each element owned by exactly one thread -> no hazard).
// LDS: 13312(h2b) + 25600(actb) = 38912 B -> 4 blocks/CU (was 64512 -> 2).
// ---------------------------------------------------------------------------
static constexpr int MLDH  = 104;  // h2b stride (shorts)
static constexpr int MLDA  = 200;  // actb stride (shorts)

__global__ __launch_bounds__(256, 4) void mlp_mfma(
    float* __restrict__ xio,
    const float* __restrict__ ln2w, const float* __restrict__ ln2b,
    const short* __restrict__ w1b, const float* __restrict__ b1,
    const short* __restrict__ w2b, const float* __restrict__ b2)
{
    __shared__ __align__(16) short h2b[64 * MLDH];
    __shared__ __align__(16) short actb[64 * MLDA];

    const int tid    = threadIdx.x;
    const int token0 = blockIdx.x * 64;
    const int lane   = tid & 63;
    const int wv     = __builtin_amdgcn_readfirstlane(tid >> 6);
    const int lr     = lane & 15;
    const int lk     = lane >> 4;

    // ---- LN2 entirely in registers ----
    {
        const int l = tid >> 2, p = tid & 3;
        const float* xp = xio + (size_t)(token0 + l) * 96 + p * 24;
        float v[24];
        #pragma unroll
        for (int j = 0; j < 6; ++j) {
            float4 t = ((const float4*)xp)[j];
            v[4*j+0] = t.x; v[4*j+1] = t.y; v[4*j+2] = t.z; v[4*j+3] = t.w;
        }
        float s0 = 0.f, s1 = 0.f;
        #pragma unroll
        for (int c0 = 0; c0 < 24; ++c0) { s0 += v[c0]; s1 += v[c0] * v[c0]; }
        s0 += __shfl_xor(s0, 1); s1 += __shfl_xor(s1, 1);
        s0 += __shfl_xor(s0, 2); s1 += __shfl_xor(s1, 2);
        float mean = s0 * (1.f / 96.f);
        float var  = fmaxf(s1 * (1.f / 96.f) - mean * mean, 0.f);
        float rstd = rsqrtf(var + 1e-5f);
        #pragma unroll
        for (int c0 = 0; c0 < 24; ++c0) {
            int c = p * 24 + c0;
            h2b[l * MLDH + c] = f2bf((v[c0] - mean) * rstd * ln2w[c] + ln2b[c]);
        }
    }
    __syncthreads();

    bf16x8 a1[4][3];
    #pragma unroll
    for (int rt = 0; rt < 4; ++rt)
        #pragma unroll
        for (int ks = 0; ks < 3; ++ks)
            a1[rt][ks] = *(const bf16x8*)&h2b[(rt * 16 + lr) * MLDH + ks * 32 + lk * 8];

    f32x4 acc2[6];
    #pragma unroll
    for (int ct = 0; ct < 6; ++ct) acc2[ct] = (f32x4){0.f, 0.f, 0.f, 0.f};

    for (int half = 0; half < 2; ++half) {
        if (half) __syncthreads();

        const int oc0w = half * 192 + wv * 48;
        f32x4 acc1[4][3];
        #pragma unroll
        for (int rt = 0; rt < 4; ++rt)
            #pragma unroll
            for (int ct = 0; ct < 3; ++ct) acc1[rt][ct] = (f32x4){0.f, 0.f, 0.f, 0.f};

        #pragma unroll
        for (int ct = 0; ct < 3; ++ct) {
            const short* bp = w1b + (oc0w + ct * 16 + lr) * 96 + lk * 8;
            bf16x8 bg0 = *(const bf16x8*)(bp);
            bf16x8 bg1 = *(const bf16x8*)(bp + 32);
            bf16x8 bg2 = *(const bf16x8*)(bp + 64);
            #pragma unroll
            for (int rt = 0; rt < 4; ++rt) {
                acc1[rt][ct] = __builtin_amdgcn_mfma_f32_16x16x32_bf16(a1[rt][0], bg0, acc1[rt][ct], 0, 0, 0);
                acc1[rt][ct] = __builtin_amdgcn_mfma_f32_16x16x32_bf16(a1[rt][1], bg1, acc1[rt][ct], 0, 0, 0);
                acc1[rt][ct] = __builtin_amdgcn_mfma_f32_16x16x32_bf16(a1[rt][2], bg2, acc1[rt][ct], 0, 0, 0);
            }
        }

        #pragma unroll
        for (int ct = 0; ct < 3; ++ct) {
            float bias = b1[oc0w + ct * 16 + lr];
            #pragma unroll
            for (int rt = 0; rt < 4; ++rt) {
                #pragma unroll
                for (int r = 0; r < 4; ++r) {
                    float a = acc1[rt][ct][r] + bias;
                    float g = 0.5f * a * (1.f + erff(a * 0.70710678118654752f));
                    actb[(rt * 16 + lk * 4 + r) * MLDA + wv * 48 + ct * 16 + lr] = f2bf(g);
                }
            }
        }
        __syncthreads();

        #pragma unroll 2
        for (int ks = 0; ks < 6; ++ks) {
            bf16x8 a2 = *(const bf16x8*)&actb[(wv * 16 + lr) * MLDA + ks * 32 + lk * 8];
            #pragma unroll
            for (int ct = 0; ct < 6; ++ct) {
                bf16x8 bw = *(const bf16x8*)(w2b + (ct * 16 + lr) * 384 + half * 192 + ks * 32 + lk * 8);
                acc2[ct] = __builtin_amdgcn_mfma_f32_16x16x32_bf16(a2, bw, acc2[ct], 0, 0, 0);
            }
        }
    }

    // ---- epilogue: residual re-read from global (L2-hot), same-thread RMW ----
    #pragma unroll
    for (int ct = 0; ct < 6; ++ct) {
        int col = ct * 16 + lr;
        float bias = b2[col];
        #pragma unroll
        for (int r = 0; r < 4; ++r) {
            int row = wv * 16 + lk * 4 + r;
            size_t a = (size_t)(token0 + row) * 96 + col;
            xio[a] = acc2[ct][r] + xio[a] + bias;
        }
    }
}

// ---------------------------------------------------------------------------
extern "C" void kernel_launch(void* const* d_in, const int* in_sizes, int n_in,
                              void* d_out, int out_size, void* d_ws, size_t ws_size,
                              hipStream_t stream) {
    const float* x    = (const float*)d_in[0];
    const float* ln1w = (const float*)d_in[1];
    const float* ln1b = (const float*)d_in[2];
    const float* wqkv = (const float*)d_in[3];   // [288,96]
    const float* bqkv = (const float*)d_in[4];
    const float* wo   = (const float*)d_in[5];   // [96,96]
    const float* bo   = (const float*)d_in[6];
    const float* ln2w = (const float*)d_in[7];
    const float* ln2b = (const float*)d_in[8];
    const float* w1   = (const float*)d_in[9];   // [384,96]
    const float* b1   = (const float*)d_in[10];
    const float* w2   = (const float*)d_in[11];  // [96,384]
    const float* b2   = (const float*)d_in[12];
    float* out = (float*)d_out;

    short* ws  = (short*)d_ws;
    short* wqb = ws;            // 27648
    short* wob = ws + 27648;    // 9216
    short* w1b = ws + 36864;    // 36864
    short* w2b = ws + 73728;    // 36864   (total 221184 B)

    prep_bf16<<<432, 256, 0, stream>>>(wqkv, wo, w1, w2, ws);
    attn_mfma<<<NW, 256, 0, stream>>>(x, ln1w, ln1b, wqb, bqkv, wob, bo, out);
    mlp_mfma<<<3136, 256, 0, stream>>>(out, ln2w, ln2b, w1b, b1, w2b, b2);
}

// Round 2
// 274.161 us; speedup vs baseline: 1.1969x; 1.1381x over previous
//
#include <hip/hip_runtime.h>
#include <math.h>

// Problem constants (SwinBlock: B=4, H=W=224, C=96, WS=8, shift=4, NH=3, hd=32)
static constexpr int Hn   = 224;
static constexpr int Wn   = 224;
static constexpr int Cn   = 96;
static constexpr int Sft  = 4;     // WS/2
static constexpr int NWH  = 28;    // 224/8
static constexpr int NWPB = 784;   // 28*28
static constexpr int NW   = 3136;  // 4*784

typedef __attribute__((ext_vector_type(8))) short bf16x8;  // 8 bf16 in 4 VGPRs
typedef __attribute__((ext_vector_type(4))) float f32x4;
typedef __attribute__((ext_vector_type(4))) short s16x4;

__device__ inline short f2bf(float f) {            // RNE float->bf16
    unsigned u = __float_as_uint(f);
    return (short)((u + 0x7fffu + ((u >> 16) & 1u)) >> 16);
}

// Fast erf-based GELU (A&S 7.1.26, |eps_erf| <= 1.5e-7 -> invisible under the
// bf16 rounding that immediately follows; replaces the huge inline erff).
__device__ inline float gelu_f(float a) {
    float u  = a * 0.70710678118654752f;
    float au = fabsf(u);
    float t  = __builtin_amdgcn_rcpf(fmaf(0.3275911f, au, 1.f));
    float e  = __expf(-u * u);
    float p  = t * fmaf(t, fmaf(t, fmaf(t, fmaf(t, 1.061405429f,
                        -1.453152027f), 1.421413741f), -0.284496736f),
                        0.254829592f);
    float er = fmaf(-p, e, 1.f);          // erf(|u|)
    er = (u < 0.f) ? -er : er;
    return 0.5f * a * (1.f + er);
}

// ---------------------------------------------------------------------------
// K0: convert ALL weights to bf16 into ws.
// layout (shorts): wqb[27648] | wob[9216] | w1b[36864] | w2b[36864]  (221184 B)
// All row-major [oc][k] -> K contiguous for B-fragments.
// ---------------------------------------------------------------------------
__global__ void prep_bf16(const float* __restrict__ wqkv, const float* __restrict__ wo,
                          const float* __restrict__ w1,   const float* __restrict__ w2,
                          short* __restrict__ ws) {
    int idx = blockIdx.x * 256 + threadIdx.x;
    if (idx < 27648)        ws[idx] = f2bf(wqkv[idx]);
    else if (idx < 36864)   ws[idx] = f2bf(wo[idx - 27648]);
    else if (idx < 73728)   ws[idx] = f2bf(w1[idx - 36864]);
    else if (idx < 110592)  ws[idx] = f2bf(w2[idx - 73728]);
}

// ---------------------------------------------------------------------------
// K1 (R2: FUSED attn+mlp). One block = one 8x8 window (64 tokens), 4 waves.
// The MLP is strictly per-token (roll/window-reverse is only a permutation),
// so it runs on the window's own 64 tokens right after out-proj, reading the
// post-attention x from LDS (st) for BOTH LN2 and the residual. The
// intermediate never touches global memory; out is written exactly once.
//
// Fragment layouts (mfma_f32_16x16x32_bf16, m89-verified):
//  A: row=lane&15, k=(lane>>4)*8+j ; B: col=lane&15, same k ;
//  D: col=lane&15, row=(lane>>4)*4+r
//
// LDS unions (time-shared):
//  U[25600]    : xf f32 -> Q|K bf16 -> P bf16 -> st f32 (residual+LN2 source,
//                live to the end; final result added in-place)
//  h2b[13312]  : LN1-out -> O -> LN2-out
//  vtact[25600]: vt (V^T, first 13824 B) -> actb (GELU acts, per-half)
//  total 25600+13312+25600+256 = 64768 B -> 2 blocks/CU.
// ---------------------------------------------------------------------------
static constexpr int LDH  = 104;  // h2b stride (shorts)
static constexpr int LDQK = 200;  // U as Q|K: stride (shorts): Q[0..95] K[96..191] pad8
static constexpr int LDVT = 72;   // vt stride (shorts): [ch 96][tok 64 pad8]
static constexpr int LDP  = 200;  // U as P: [tok][h*64+kv] pad8 (shorts)
static constexpr int LDXF = 100;  // U as xf: stride (floats)
static constexpr int LDST = 100;  // U as st: stride (floats)
static constexpr int LDA  = 200;  // actb stride (shorts), one half (192+8)

__global__ __launch_bounds__(256, 2) void attn_mlp(
    const float* __restrict__ x,
    const float* __restrict__ ln1w, const float* __restrict__ ln1b,
    const short* __restrict__ wqb,  const float* __restrict__ bqkv,
    const short* __restrict__ wob,  const float* __restrict__ bo,
    const float* __restrict__ ln2w, const float* __restrict__ ln2b,
    const short* __restrict__ w1b,  const float* __restrict__ b1,
    const short* __restrict__ w2b,  const float* __restrict__ b2,
    float* __restrict__ out)
{
    __shared__ __align__(16) char  U[64 * 400];        // xf -> Q|K -> P -> st
    __shared__ __align__(16) short h2b[64 * LDH];      // LN1 -> O -> LN2
    __shared__ __align__(16) short vtact[64 * LDA];    // vt -> actb
    __shared__ int   tbase[64];

    const int blk = blockIdx.x;
    const int b   = blk / NWPB;
    const int rem = blk - b * NWPB;
    const int wh  = rem / NWH;
    const int ww  = rem - wh * NWH;
    const int tid  = threadIdx.x;
    const int lane = tid & 63;
    const int wv   = __builtin_amdgcn_readfirstlane(tid >> 6);
    const int lr   = lane & 15;
    const int lk   = lane >> 4;

    if (tid < 64) {
        int i = tid >> 3, j = tid & 7;
        int hs = wh * 8 + i + Sft; if (hs >= Hn) hs -= Hn;
        int ws2 = ww * 8 + j + Sft; if (ws2 >= Wn) ws2 -= Wn;
        tbase[tid] = ((b * Hn + hs) * Wn + ws2) * Cn;
    }
    __syncthreads();

    // ---- P1: load x [64][96] (float4, 16B-aligned rows) into U as xf ----
    float* xf = (float*)U;
    for (int i = tid; i < 64 * 24; i += 256) {
        int row = i / 24, c4 = i - row * 24;
        float4 v = ((const float4*)(x + tbase[row]))[c4];
        *(float4*)&xf[row * LDXF + c4 * 4] = v;
    }
    __syncthreads();

    // ---- P2: LN1 (4 lanes/token; wave wv covers exactly token tile wv) ----
    {
        const int l = tid >> 2, p = tid & 3;
        float s0 = 0.f, s1 = 0.f;
        #pragma unroll
        for (int c0 = 0; c0 < 24; ++c0) {
            float v = xf[l * LDXF + p * 24 + c0];
            s0 += v; s1 += v * v;
        }
        s0 += __shfl_xor(s0, 1); s1 += __shfl_xor(s1, 1);
        s0 += __shfl_xor(s0, 2); s1 += __shfl_xor(s1, 2);
        float mean = s0 * (1.f / 96.f);
        float var  = fmaxf(s1 * (1.f / 96.f) - mean * mean, 0.f);
        float rstd = rsqrtf(var + 1e-5f);
        #pragma unroll
        for (int c0 = 0; c0 < 24; ++c0) {
            int c = p * 24 + c0;
            float v = xf[l * LDXF + c];
            h2b[l * LDH + c] = f2bf((v - mean) * rstd * ln1w[c] + ln1b[c]);
        }
    }
    __syncthreads();   // h2b ready; also fences xf reads before Q/K overwrite

    // ---- P3: QKV GEMM. wave -> row-tile wv (16 tokens), 18 col-tiles of 16 ----
    short* qk = (short*)U;
    short* vt = vtact;
    {
        bf16x8 a0 = *(const bf16x8*)&h2b[(wv * 16 + lr) * LDH +  0 + lk * 8];
        bf16x8 a1 = *(const bf16x8*)&h2b[(wv * 16 + lr) * LDH + 32 + lk * 8];
        bf16x8 a2 = *(const bf16x8*)&h2b[(wv * 16 + lr) * LDH + 64 + lk * 8];
        #pragma unroll 6
        for (int ct = 0; ct < 18; ++ct) {
            const short* bp = wqb + (ct * 16 + lr) * 96 + lk * 8;
            bf16x8 b0 = *(const bf16x8*)(bp);
            bf16x8 b1 = *(const bf16x8*)(bp + 32);
            bf16x8 b2 = *(const bf16x8*)(bp + 64);
            f32x4 acc = (f32x4){0.f, 0.f, 0.f, 0.f};
            acc = __builtin_amdgcn_mfma_f32_16x16x32_bf16(a0, b0, acc, 0, 0, 0);
            acc = __builtin_amdgcn_mfma_f32_16x16x32_bf16(a1, b1, acc, 0, 0, 0);
            acc = __builtin_amdgcn_mfma_f32_16x16x32_bf16(a2, b2, acc, 0, 0, 0);
            const int col  = ct * 16 + lr;
            const float bs = bqkv[col];                // L2-hot global
            if (ct < 12) {            // Q,K -> [tok][ch] in U
                #pragma unroll
                for (int r = 0; r < 4; ++r)
                    qk[(wv * 16 + lk * 4 + r) * LDQK + col] = f2bf(acc[r] + bs);
            } else {                  // V -> transposed [ch][tok], packed b64
                s16x4 pk;
                #pragma unroll
                for (int r = 0; r < 4; ++r) pk[r] = f2bf(acc[r] + bs);
                *(s16x4*)&vt[(col - 192) * LDVT + wv * 16 + lk * 4] = pk;
            }
        }
    }
    __syncthreads();   // Q,K,V visible to all waves

    // ---- P4: S = QK^T per head (wave -> query row-tile wv), softmax ----
    short* pb = (short*)U;   // P overwrites Q|K after the barrier below
    {
        f32x4 accs[3][4];
        #pragma unroll
        for (int h = 0; h < 3; ++h) {
            bf16x8 aq = *(const bf16x8*)&qk[(wv * 16 + lr) * LDQK + h * 32 + lk * 8];
            #pragma unroll
            for (int ct = 0; ct < 4; ++ct) {
                bf16x8 bk = *(const bf16x8*)&qk[(ct * 16 + lr) * LDQK + 96 + h * 32 + lk * 8];
                f32x4 z = (f32x4){0.f, 0.f, 0.f, 0.f};
                accs[h][ct] = __builtin_amdgcn_mfma_f32_16x16x32_bf16(aq, bk, z, 0, 0, 0);
            }
        }
        __syncthreads();   // every wave done reading K -> P may overwrite U

        const float scale = 0.17677669529663687f;  // 1/sqrt(32)
        float inv[3][4];
        #pragma unroll
        for (int h = 0; h < 3; ++h) {
            #pragma unroll
            for (int r = 0; r < 4; ++r) {
                float m = fmaxf(fmaxf(accs[h][0][r], accs[h][1][r]),
                                fmaxf(accs[h][2][r], accs[h][3][r]));
                m = fmaxf(m, __shfl_xor(m, 1));
                m = fmaxf(m, __shfl_xor(m, 2));
                m = fmaxf(m, __shfl_xor(m, 4));
                m = fmaxf(m, __shfl_xor(m, 8));
                float s = 0.f;
                #pragma unroll
                for (int ct = 0; ct < 4; ++ct) {
                    float p = __expf((accs[h][ct][r] - m) * scale);
                    accs[h][ct][r] = p; s += p;
                }
                s += __shfl_xor(s, 1); s += __shfl_xor(s, 2);
                s += __shfl_xor(s, 4); s += __shfl_xor(s, 8);
                inv[h][r] = 1.f / s;
            }
        }
        // P -> bf16 LDS (rows of own wave only; no barrier needed)
        #pragma unroll
        for (int h = 0; h < 3; ++h)
            #pragma unroll
            for (int ct = 0; ct < 4; ++ct)
                #pragma unroll
                for (int r = 0; r < 4; ++r)
                    pb[(wv * 16 + lk * 4 + r) * LDP + h * 64 + ct * 16 + lr] =
                        f2bf(accs[h][ct][r]);

        // ---- P5: O = P V (deferred 1/sum), write O bf16 into h2b ----
        f32x4 acco[3][2];
        #pragma unroll
        for (int h = 0; h < 3; ++h)
            #pragma unroll
            for (int ct = 0; ct < 2; ++ct) acco[h][ct] = (f32x4){0.f, 0.f, 0.f, 0.f};
        #pragma unroll
        for (int h = 0; h < 3; ++h) {
            #pragma unroll
            for (int ks = 0; ks < 2; ++ks) {
                bf16x8 ap = *(const bf16x8*)&pb[(wv * 16 + lr) * LDP + h * 64 + ks * 32 + lk * 8];
                #pragma unroll
                for (int ct = 0; ct < 2; ++ct) {
                    bf16x8 bv = *(const bf16x8*)&vt[(h * 32 + ct * 16 + lr) * LDVT + ks * 32 + lk * 8];
                    acco[h][ct] = __builtin_amdgcn_mfma_f32_16x16x32_bf16(ap, bv, acco[h][ct], 0, 0, 0);
                }
            }
        }
        #pragma unroll
        for (int h = 0; h < 3; ++h)
            #pragma unroll
            for (int ct = 0; ct < 2; ++ct)
                #pragma unroll
                for (int r = 0; r < 4; ++r)
                    h2b[(wv * 16 + lk * 4 + r) * LDH + h * 32 + ct * 16 + lr] =
                        f2bf(acco[h][ct][r] * inv[h][r]);
    }

    // ---- P6: out-proj -> st f32 (attention output, pre-MLP x) ----
    float* st = (float*)U;   // overwrites pb: own-wave rows, program-ordered
    {
        bf16x8 o0 = *(const bf16x8*)&h2b[(wv * 16 + lr) * LDH +  0 + lk * 8];
        bf16x8 o1 = *(const bf16x8*)&h2b[(wv * 16 + lr) * LDH + 32 + lk * 8];
        bf16x8 o2 = *(const bf16x8*)&h2b[(wv * 16 + lr) * LDH + 64 + lk * 8];
        #pragma unroll
        for (int ct = 0; ct < 6; ++ct) {
            const short* bp = wob + (ct * 16 + lr) * 96 + lk * 8;
            bf16x8 b0 = *(const bf16x8*)(bp);
            bf16x8 b1 = *(const bf16x8*)(bp + 32);
            bf16x8 b2 = *(const bf16x8*)(bp + 64);
            f32x4 acc = (f32x4){0.f, 0.f, 0.f, 0.f};
            acc = __builtin_amdgcn_mfma_f32_16x16x32_bf16(o0, b0, acc, 0, 0, 0);
            acc = __builtin_amdgcn_mfma_f32_16x16x32_bf16(o1, b1, acc, 0, 0, 0);
            acc = __builtin_amdgcn_mfma_f32_16x16x32_bf16(o2, b2, acc, 0, 0, 0);
            const int col = ct * 16 + lr;
            const float bs = bo[col];                  // L2-hot global
            #pragma unroll
            for (int r = 0; r < 4; ++r)
                st[(wv * 16 + lk * 4 + r) * LDST + col] = acc[r] + bs;
        }
    }
    // No barrier: LN2 below reads st rows [wv*16, wv*16+16) = own-wave rows,
    // written just above by this wave (program order).

    // ---- M1: LN2 from st (LDS), write h2b (own-wave rows) ----
    {
        const int l = tid >> 2, p = tid & 3;
        float s0 = 0.f, s1 = 0.f;
        #pragma unroll
        for (int c0 = 0; c0 < 24; ++c0) {
            float v = st[l * LDST + p * 24 + c0];
            s0 += v; s1 += v * v;
        }
        s0 += __shfl_xor(s0, 1); s1 += __shfl_xor(s1, 1);
        s0 += __shfl_xor(s0, 2); s1 += __shfl_xor(s1, 2);
        float mean = s0 * (1.f / 96.f);
        float var  = fmaxf(s1 * (1.f / 96.f) - mean * mean, 0.f);
        float rstd = rsqrtf(var + 1e-5f);
        #pragma unroll
        for (int c0 = 0; c0 < 24; ++c0) {
            int c = p * 24 + c0;
            float v = st[l * LDST + c];
            h2b[l * LDH + c] = f2bf((v - mean) * rstd * ln2w[c] + ln2b[c]);
        }
    }
    __syncthreads();   // h2b(LN2) + st complete for all waves; vt dead beyond here

    // ---- M2: MLP GEMM1 + GELU -> actb (vt region), GEMM2 -> acc2 ----
    short* actb = vtact;
    bf16x8 a1[4][3];
    #pragma unroll
    for (int rt = 0; rt < 4; ++rt)
        #pragma unroll
        for (int ks = 0; ks < 3; ++ks)
            a1[rt][ks] = *(const bf16x8*)&h2b[(rt * 16 + lr) * LDH + ks * 32 + lk * 8];

    f32x4 acc2[6];
    #pragma unroll
    for (int ct = 0; ct < 6; ++ct) acc2[ct] = (f32x4){0.f, 0.f, 0.f, 0.f};

    for (int half = 0; half < 2; ++half) {
        if (half) __syncthreads();     // all waves done reading actb(half 0)

        const int oc0w = half * 192 + wv * 48;
        f32x4 acc1[4][3];
        #pragma unroll
        for (int rt = 0; rt < 4; ++rt)
            #pragma unroll
            for (int ct = 0; ct < 3; ++ct) acc1[rt][ct] = (f32x4){0.f, 0.f, 0.f, 0.f};

        #pragma unroll
        for (int ct = 0; ct < 3; ++ct) {
            const short* bp = w1b + (oc0w + ct * 16 + lr) * 96 + lk * 8;
            bf16x8 bg0 = *(const bf16x8*)(bp);
            bf16x8 bg1 = *(const bf16x8*)(bp + 32);
            bf16x8 bg2 = *(const bf16x8*)(bp + 64);
            #pragma unroll
            for (int rt = 0; rt < 4; ++rt) {
                acc1[rt][ct] = __builtin_amdgcn_mfma_f32_16x16x32_bf16(a1[rt][0], bg0, acc1[rt][ct], 0, 0, 0);
                acc1[rt][ct] = __builtin_amdgcn_mfma_f32_16x16x32_bf16(a1[rt][1], bg1, acc1[rt][ct], 0, 0, 0);
                acc1[rt][ct] = __builtin_amdgcn_mfma_f32_16x16x32_bf16(a1[rt][2], bg2, acc1[rt][ct], 0, 0, 0);
            }
        }

        #pragma unroll
        for (int ct = 0; ct < 3; ++ct) {
            float bias = b1[oc0w + ct * 16 + lr];
            #pragma unroll
            for (int rt = 0; rt < 4; ++rt) {
                #pragma unroll
                for (int r = 0; r < 4; ++r) {
                    float g = gelu_f(acc1[rt][ct][r] + bias);
                    actb[(rt * 16 + lk * 4 + r) * LDA + wv * 48 + ct * 16 + lr] = f2bf(g);
                }
            }
        }
        __syncthreads();               // actb(half) ready for all waves

        #pragma unroll 2
        for (int ks = 0; ks < 6; ++ks) {
            bf16x8 a2 = *(const bf16x8*)&actb[(wv * 16 + lr) * LDA + ks * 32 + lk * 8];
            #pragma unroll
            for (int ct = 0; ct < 6; ++ct) {
                bf16x8 bw = *(const bf16x8*)(w2b + (ct * 16 + lr) * 384 + half * 192 + ks * 32 + lk * 8);
                acc2[ct] = __builtin_amdgcn_mfma_f32_16x16x32_bf16(a2, bw, acc2[ct], 0, 0, 0);
            }
        }
    }

    // ---- M3: residual + bias into st in-place (own-wave rows) ----
    #pragma unroll
    for (int ct = 0; ct < 6; ++ct) {
        const int col = ct * 16 + lr;
        const float bias = b2[col];
        #pragma unroll
        for (int r = 0; r < 4; ++r) {
            const int row = wv * 16 + lk * 4 + r;
            st[row * LDST + col] += acc2[ct][r] + bias;
        }
    }
    __syncthreads();

    // ---- P7: coalesced write-back; un-roll cancels the roll ----
    for (int i = tid; i < 64 * 96; i += 256) {
        int l = i / 96, c = i - l * 96;
        out[tbase[l] + c] = st[l * LDST + c];
    }
}

// ---------------------------------------------------------------------------
extern "C" void kernel_launch(void* const* d_in, const int* in_sizes, int n_in,
                              void* d_out, int out_size, void* d_ws, size_t ws_size,
                              hipStream_t stream) {
    const float* x    = (const float*)d_in[0];
    const float* ln1w = (const float*)d_in[1];
    const float* ln1b = (const float*)d_in[2];
    const float* wqkv = (const float*)d_in[3];   // [288,96]
    const float* bqkv = (const float*)d_in[4];
    const float* wo   = (const float*)d_in[5];   // [96,96]
    const float* bo   = (const float*)d_in[6];
    const float* ln2w = (const float*)d_in[7];
    const float* ln2b = (const float*)d_in[8];
    const float* w1   = (const float*)d_in[9];   // [384,96]
    const float* b1   = (const float*)d_in[10];
    const float* w2   = (const float*)d_in[11];  // [96,384]
    const float* b2   = (const float*)d_in[12];
    float* out = (float*)d_out;

    short* ws  = (short*)d_ws;
    short* wqb = ws;            // 27648
    short* wob = ws + 27648;    // 9216
    short* w1b = ws + 36864;    // 36864
    short* w2b = ws + 73728;    // 36864   (total 221184 B)

    prep_bf16<<<432, 256, 0, stream>>>(wqkv, wo, w1, w2, ws);
    attn_mlp<<<NW, 256, 0, stream>>>(x, ln1w, ln1b, wqb, bqkv, wob, bo,
                                     ln2w, ln2b, w1b, b1, w2b, b2, out);
}

// Round 3
// 191.286 us; speedup vs baseline: 1.7154x; 1.4332x over previous
//
#include <hip/hip_runtime.h>
#include <math.h>

// Problem constants (SwinBlock: B=4, H=W=224, C=96, WS=8, shift=4, NH=3, hd=32)
static constexpr int Hn   = 224;
static constexpr int Wn   = 224;
static constexpr int Cn   = 96;
static constexpr int Sft  = 4;     // WS/2
static constexpr int NWH  = 28;    // 224/8
static constexpr int NWPB = 784;   // 28*28
static constexpr int NW   = 3136;  // 4*784

typedef __attribute__((ext_vector_type(8))) short bf16x8;  // 8 bf16 in 4 VGPRs
typedef __attribute__((ext_vector_type(4))) float f32x4;
typedef __attribute__((ext_vector_type(4))) short s16x4;

__device__ inline short f2bf(float f) {            // RNE float->bf16
    unsigned u = __float_as_uint(f);
    return (short)((u + 0x7fffu + ((u >> 16) & 1u)) >> 16);
}

// Fast erf-based GELU (A&S 7.1.26, |eps_erf| <= 1.5e-7 -> invisible under the
// bf16 rounding that immediately follows).
__device__ inline float gelu_f(float a) {
    float u  = a * 0.70710678118654752f;
    float au = fabsf(u);
    float t  = __builtin_amdgcn_rcpf(fmaf(0.3275911f, au, 1.f));
    float e  = __expf(-u * u);
    float p  = t * fmaf(t, fmaf(t, fmaf(t, fmaf(t, 1.061405429f,
                        -1.453152027f), 1.421413741f), -0.284496736f),
                        0.254829592f);
    float er = fmaf(-p, e, 1.f);          // erf(|u|)
    er = (u < 0.f) ? -er : er;
    return 0.5f * a * (1.f + er);
}

// ---------------------------------------------------------------------------
// K0: convert ALL weights to bf16 into ws.
// layout (shorts): wqb[27648] | wob[9216] | w1b[36864] | w2b[36864]  (221184 B)
// ---------------------------------------------------------------------------
__global__ void prep_bf16(const float* __restrict__ wqkv, const float* __restrict__ wo,
                          const float* __restrict__ w1,   const float* __restrict__ w2,
                          short* __restrict__ ws) {
    int idx = blockIdx.x * 256 + threadIdx.x;
    if (idx < 27648)        ws[idx] = f2bf(wqkv[idx]);
    else if (idx < 36864)   ws[idx] = f2bf(wo[idx - 27648]);
    else if (idx < 73728)   ws[idx] = f2bf(w1[idx - 36864]);
    else if (idx < 110592)  ws[idx] = f2bf(w2[idx - 73728]);
}

// ---------------------------------------------------------------------------
// K1 (R3): fused attn+mlp, 3 blocks/CU.
//  - act buffer shrunk to a 96-col QUARTER (fits dead vt region) -> LDS
//    52992 B -> 3 blocks/CU (was 65024 -> 2).
//  - QKV GEMM (P3) and MLP GEMM2 use a 2x2 wave split (32 rows x half cols):
//    global B-loads per MFMA halved (1:1 -> 1:2).
// Fragment layouts (mfma_f32_16x16x32_bf16, m89-verified):
//  A: row=lane&15, k=(lane>>4)*8+j ; B: col=lane&15, same k ;
//  D: col=lane&15, row=(lane>>4)*4+r
// LDS unions (time-shared):
//  U[25600]   : xf f32 -> Q|K bf16 -> P bf16 -> st f32 (lives to the end)
//  h2b[13312] : LN1-out -> O -> LN2-out
//  vtact[13824]: vt (V^T) -> actQ (GELU acts, one 96-col quarter)
// ---------------------------------------------------------------------------
static constexpr int LDH  = 104;  // h2b stride (shorts)
static constexpr int LDQK = 200;  // U as Q|K: stride (shorts): Q[0..95] K[96..191] pad8
static constexpr int LDVT = 72;   // vt stride (shorts): [ch 96][tok 64 pad8]
static constexpr int LDP  = 200;  // U as P: [tok][h*64+kv] pad8 (shorts)
static constexpr int LDXF = 100;  // U as xf: stride (floats)
static constexpr int LDST = 100;  // U as st: stride (floats)
static constexpr int LDAQ = 104;  // actQ stride (shorts), one 96-col quarter

__global__ __launch_bounds__(256, 3) void attn_mlp(
    const float* __restrict__ x,
    const float* __restrict__ ln1w, const float* __restrict__ ln1b,
    const short* __restrict__ wqb,  const float* __restrict__ bqkv,
    const short* __restrict__ wob,  const float* __restrict__ bo,
    const float* __restrict__ ln2w, const float* __restrict__ ln2b,
    const short* __restrict__ w1b,  const float* __restrict__ b1,
    const short* __restrict__ w2b,  const float* __restrict__ b2,
    float* __restrict__ out)
{
    __shared__ __align__(16) char  U[64 * 400];        // xf -> Q|K -> P -> st
    __shared__ __align__(16) short h2b[64 * LDH];      // LN1 -> O -> LN2
    __shared__ __align__(16) short vtact[96 * LDVT];   // vt -> actQ (64*LDAQ fits)
    __shared__ int   tbase[64];

    const int blk = blockIdx.x;
    const int b   = blk / NWPB;
    const int rem = blk - b * NWPB;
    const int wh  = rem / NWH;
    const int ww  = rem - wh * NWH;
    const int tid  = threadIdx.x;
    const int lane = tid & 63;
    const int wv   = __builtin_amdgcn_readfirstlane(tid >> 6);
    const int lr   = lane & 15;
    const int lk   = lane >> 4;
    const int wr   = wv >> 1;   // 2x2 wave split: row group (32 rows)
    const int wc   = wv & 1;    //                 col group

    if (tid < 64) {
        int i = tid >> 3, j = tid & 7;
        int hs = wh * 8 + i + Sft; if (hs >= Hn) hs -= Hn;
        int ws2 = ww * 8 + j + Sft; if (ws2 >= Wn) ws2 -= Wn;
        tbase[tid] = ((b * Hn + hs) * Wn + ws2) * Cn;
    }
    __syncthreads();

    // ---- P1: load x [64][96] (float4, 16B-aligned rows) into U as xf ----
    float* xf = (float*)U;
    for (int i = tid; i < 64 * 24; i += 256) {
        int row = i / 24, c4 = i - row * 24;
        float4 v = ((const float4*)(x + tbase[row]))[c4];
        *(float4*)&xf[row * LDXF + c4 * 4] = v;
    }
    __syncthreads();

    // ---- P2: LN1 (4 lanes/token) ----
    {
        const int l = tid >> 2, p = tid & 3;
        float s0 = 0.f, s1 = 0.f;
        #pragma unroll
        for (int c0 = 0; c0 < 24; ++c0) {
            float v = xf[l * LDXF + p * 24 + c0];
            s0 += v; s1 += v * v;
        }
        s0 += __shfl_xor(s0, 1); s1 += __shfl_xor(s1, 1);
        s0 += __shfl_xor(s0, 2); s1 += __shfl_xor(s1, 2);
        float mean = s0 * (1.f / 96.f);
        float var  = fmaxf(s1 * (1.f / 96.f) - mean * mean, 0.f);
        float rstd = rsqrtf(var + 1e-5f);
        #pragma unroll
        for (int c0 = 0; c0 < 24; ++c0) {
            int c = p * 24 + c0;
            float v = xf[l * LDXF + c];
            h2b[l * LDH + c] = f2bf((v - mean) * rstd * ln1w[c] + ln1b[c]);
        }
    }
    __syncthreads();   // h2b ready; xf dead (fences Q/K overwrite)

    // ---- P3: QKV GEMM, 2x2 split: rows wr*32 (2 rt), col-tiles wc*9..wc*9+8 ----
    short* qk = (short*)U;
    short* vt = vtact;
    {
        bf16x8 aq[2][3];
        #pragma unroll
        for (int rt = 0; rt < 2; ++rt)
            #pragma unroll
            for (int ks = 0; ks < 3; ++ks)
                aq[rt][ks] = *(const bf16x8*)&h2b[(wr * 32 + rt * 16 + lr) * LDH + ks * 32 + lk * 8];

        #pragma unroll 3
        for (int ct9 = 0; ct9 < 9; ++ct9) {
            const int ct = wc * 9 + ct9;
            const short* bp = wqb + (ct * 16 + lr) * 96 + lk * 8;
            bf16x8 b0 = *(const bf16x8*)(bp);
            bf16x8 b1 = *(const bf16x8*)(bp + 32);
            bf16x8 b2 = *(const bf16x8*)(bp + 64);
            const int col  = ct * 16 + lr;
            const float bs = bqkv[col];                // L2-hot global
            #pragma unroll
            for (int rt = 0; rt < 2; ++rt) {
                f32x4 acc = (f32x4){0.f, 0.f, 0.f, 0.f};
                acc = __builtin_amdgcn_mfma_f32_16x16x32_bf16(aq[rt][0], b0, acc, 0, 0, 0);
                acc = __builtin_amdgcn_mfma_f32_16x16x32_bf16(aq[rt][1], b1, acc, 0, 0, 0);
                acc = __builtin_amdgcn_mfma_f32_16x16x32_bf16(aq[rt][2], b2, acc, 0, 0, 0);
                const int rb = wr * 32 + rt * 16;
                if (ct < 12) {            // Q,K -> [tok][ch] in U
                    #pragma unroll
                    for (int r = 0; r < 4; ++r)
                        qk[(rb + lk * 4 + r) * LDQK + col] = f2bf(acc[r] + bs);
                } else {                  // V -> transposed [ch][tok], packed b64
                    s16x4 pk;
                    #pragma unroll
                    for (int r = 0; r < 4; ++r) pk[r] = f2bf(acc[r] + bs);
                    *(s16x4*)&vt[(col - 192) * LDVT + rb + lk * 4] = pk;
                }
            }
        }
    }
    __syncthreads();   // Q,K,V visible to all waves

    // ---- P4: S = QK^T per head (wave -> query row-tile wv), softmax ----
    short* pb = (short*)U;   // P overwrites Q|K after the barrier below
    {
        f32x4 accs[3][4];
        #pragma unroll
        for (int h = 0; h < 3; ++h) {
            bf16x8 aqf = *(const bf16x8*)&qk[(wv * 16 + lr) * LDQK + h * 32 + lk * 8];
            #pragma unroll
            for (int ct = 0; ct < 4; ++ct) {
                bf16x8 bk = *(const bf16x8*)&qk[(ct * 16 + lr) * LDQK + 96 + h * 32 + lk * 8];
                f32x4 z = (f32x4){0.f, 0.f, 0.f, 0.f};
                accs[h][ct] = __builtin_amdgcn_mfma_f32_16x16x32_bf16(aqf, bk, z, 0, 0, 0);
            }
        }
        __syncthreads();   // every wave done reading K -> P may overwrite U

        const float scale = 0.17677669529663687f;  // 1/sqrt(32)
        float inv[3][4];
        #pragma unroll
        for (int h = 0; h < 3; ++h) {
            #pragma unroll
            for (int r = 0; r < 4; ++r) {
                float m = fmaxf(fmaxf(accs[h][0][r], accs[h][1][r]),
                                fmaxf(accs[h][2][r], accs[h][3][r]));
                m = fmaxf(m, __shfl_xor(m, 1));
                m = fmaxf(m, __shfl_xor(m, 2));
                m = fmaxf(m, __shfl_xor(m, 4));
                m = fmaxf(m, __shfl_xor(m, 8));
                float s = 0.f;
                #pragma unroll
                for (int ct = 0; ct < 4; ++ct) {
                    float p = __expf((accs[h][ct][r] - m) * scale);
                    accs[h][ct][r] = p; s += p;
                }
                s += __shfl_xor(s, 1); s += __shfl_xor(s, 2);
                s += __shfl_xor(s, 4); s += __shfl_xor(s, 8);
                inv[h][r] = 1.f / s;
            }
        }
        // P -> bf16 LDS (rows of own wave only; no barrier needed)
        #pragma unroll
        for (int h = 0; h < 3; ++h)
            #pragma unroll
            for (int ct = 0; ct < 4; ++ct)
                #pragma unroll
                for (int r = 0; r < 4; ++r)
                    pb[(wv * 16 + lk * 4 + r) * LDP + h * 64 + ct * 16 + lr] =
                        f2bf(accs[h][ct][r]);

        // ---- P5: O = P V (deferred 1/sum), write O bf16 into h2b ----
        f32x4 acco[3][2];
        #pragma unroll
        for (int h = 0; h < 3; ++h)
            #pragma unroll
            for (int ct = 0; ct < 2; ++ct) acco[h][ct] = (f32x4){0.f, 0.f, 0.f, 0.f};
        #pragma unroll
        for (int h = 0; h < 3; ++h) {
            #pragma unroll
            for (int ks = 0; ks < 2; ++ks) {
                bf16x8 ap = *(const bf16x8*)&pb[(wv * 16 + lr) * LDP + h * 64 + ks * 32 + lk * 8];
                #pragma unroll
                for (int ct = 0; ct < 2; ++ct) {
                    bf16x8 bv = *(const bf16x8*)&vt[(h * 32 + ct * 16 + lr) * LDVT + ks * 32 + lk * 8];
                    acco[h][ct] = __builtin_amdgcn_mfma_f32_16x16x32_bf16(ap, bv, acco[h][ct], 0, 0, 0);
                }
            }
        }
        #pragma unroll
        for (int h = 0; h < 3; ++h)
            #pragma unroll
            for (int ct = 0; ct < 2; ++ct)
                #pragma unroll
                for (int r = 0; r < 4; ++r)
                    h2b[(wv * 16 + lk * 4 + r) * LDH + h * 32 + ct * 16 + lr] =
                        f2bf(acco[h][ct][r] * inv[h][r]);
    }

    // ---- P6: out-proj -> st f32 (own-wave 16 rows; keeps barrier-free LN2) ----
    float* st = (float*)U;   // overwrites pb: own-wave rows, program-ordered
    {
        bf16x8 o0 = *(const bf16x8*)&h2b[(wv * 16 + lr) * LDH +  0 + lk * 8];
        bf16x8 o1 = *(const bf16x8*)&h2b[(wv * 16 + lr) * LDH + 32 + lk * 8];
        bf16x8 o2 = *(const bf16x8*)&h2b[(wv * 16 + lr) * LDH + 64 + lk * 8];
        #pragma unroll
        for (int ct = 0; ct < 6; ++ct) {
            const short* bp = wob + (ct * 16 + lr) * 96 + lk * 8;
            bf16x8 b0 = *(const bf16x8*)(bp);
            bf16x8 b1 = *(const bf16x8*)(bp + 32);
            bf16x8 b2 = *(const bf16x8*)(bp + 64);
            f32x4 acc = (f32x4){0.f, 0.f, 0.f, 0.f};
            acc = __builtin_amdgcn_mfma_f32_16x16x32_bf16(o0, b0, acc, 0, 0, 0);
            acc = __builtin_amdgcn_mfma_f32_16x16x32_bf16(o1, b1, acc, 0, 0, 0);
            acc = __builtin_amdgcn_mfma_f32_16x16x32_bf16(o2, b2, acc, 0, 0, 0);
            const int col = ct * 16 + lr;
            const float bs = bo[col];                  // L2-hot global
            #pragma unroll
            for (int r = 0; r < 4; ++r)
                st[(wv * 16 + lk * 4 + r) * LDST + col] = acc[r] + bs;
        }
    }
    // No barrier: LN2 reads st rows [wv*16, wv*16+16) = own-wave rows.

    // ---- M1: LN2 from st (LDS), write h2b (own-wave rows) ----
    {
        const int l = tid >> 2, p = tid & 3;
        float s0 = 0.f, s1 = 0.f;
        #pragma unroll
        for (int c0 = 0; c0 < 24; ++c0) {
            float v = st[l * LDST + p * 24 + c0];
            s0 += v; s1 += v * v;
        }
        s0 += __shfl_xor(s0, 1); s1 += __shfl_xor(s1, 1);
        s0 += __shfl_xor(s0, 2); s1 += __shfl_xor(s1, 2);
        float mean = s0 * (1.f / 96.f);
        float var  = fmaxf(s1 * (1.f / 96.f) - mean * mean, 0.f);
        float rstd = rsqrtf(var + 1e-5f);
        #pragma unroll
        for (int c0 = 0; c0 < 24; ++c0) {
            int c = p * 24 + c0;
            float v = st[l * LDST + c];
            h2b[l * LDH + c] = f2bf((v - mean) * rstd * ln2w[c] + ln2b[c]);
        }
    }
    __syncthreads();   // h2b(LN2) + st complete; vt dead beyond here

    // ---- M2: MLP. GEMM1 per half (192 cols, wave=48 cols x 64 rows, 1:4);
    //      act stored per 96-col QUARTER in actQ; GEMM2 per quarter with 2x2
    //      split (32 rows x 48 cols, 1:2). ----
    short* actQ = vtact;
    bf16x8 a1[4][3];
    #pragma unroll
    for (int rt = 0; rt < 4; ++rt)
        #pragma unroll
        for (int ks = 0; ks < 3; ++ks)
            a1[rt][ks] = *(const bf16x8*)&h2b[(rt * 16 + lr) * LDH + ks * 32 + lk * 8];

    f32x4 acc2[2][3];   // rows wr*32+rt*16, cols wc*48+ct*16
    #pragma unroll
    for (int rt = 0; rt < 2; ++rt)
        #pragma unroll
        for (int ct = 0; ct < 3; ++ct) acc2[rt][ct] = (f32x4){0.f, 0.f, 0.f, 0.f};

    for (int half = 0; half < 2; ++half) {
        const int oc0w = half * 192 + wv * 48;
        f32x4 acc1[4][3];
        #pragma unroll
        for (int rt = 0; rt < 4; ++rt)
            #pragma unroll
            for (int ct = 0; ct < 3; ++ct) acc1[rt][ct] = (f32x4){0.f, 0.f, 0.f, 0.f};

        #pragma unroll
        for (int ct = 0; ct < 3; ++ct) {
            const short* bp = w1b + (oc0w + ct * 16 + lr) * 96 + lk * 8;
            bf16x8 bg0 = *(const bf16x8*)(bp);
            bf16x8 bg1 = *(const bf16x8*)(bp + 32);
            bf16x8 bg2 = *(const bf16x8*)(bp + 64);
            #pragma unroll
            for (int rt = 0; rt < 4; ++rt) {
                acc1[rt][ct] = __builtin_amdgcn_mfma_f32_16x16x32_bf16(a1[rt][0], bg0, acc1[rt][ct], 0, 0, 0);
                acc1[rt][ct] = __builtin_amdgcn_mfma_f32_16x16x32_bf16(a1[rt][1], bg1, acc1[rt][ct], 0, 0, 0);
                acc1[rt][ct] = __builtin_amdgcn_mfma_f32_16x16x32_bf16(a1[rt][2], bg2, acc1[rt][ct], 0, 0, 0);
            }
        }

        for (int sub = 0; sub < 2; ++sub) {
            // waves whose 48 cols fall in quarter `sub` write act (bias+GELU)
            if (wr == sub) {
                #pragma unroll
                for (int ct = 0; ct < 3; ++ct) {
                    float bias = b1[oc0w + ct * 16 + lr];
                    const int lcol = wc * 48 + ct * 16 + lr;   // col within quarter
                    #pragma unroll
                    for (int rt = 0; rt < 4; ++rt) {
                        #pragma unroll
                        for (int r = 0; r < 4; ++r) {
                            float g = gelu_f(acc1[rt][ct][r] + bias);
                            actQ[(rt * 16 + lk * 4 + r) * LDAQ + lcol] = f2bf(g);
                        }
                    }
                }
            }
            __syncthreads();           // actQ(quarter) ready

            // GEMM2 slice: k = half*192 + sub*96 .. +96
            #pragma unroll
            for (int ks = 0; ks < 3; ++ks) {
                bf16x8 a2[2];
                #pragma unroll
                for (int rt = 0; rt < 2; ++rt)
                    a2[rt] = *(const bf16x8*)&actQ[(wr * 32 + rt * 16 + lr) * LDAQ + ks * 32 + lk * 8];
                #pragma unroll
                for (int ct = 0; ct < 3; ++ct) {
                    bf16x8 bw = *(const bf16x8*)(w2b + (wc * 48 + ct * 16 + lr) * 384
                                                  + half * 192 + sub * 96 + ks * 32 + lk * 8);
                    #pragma unroll
                    for (int rt = 0; rt < 2; ++rt)
                        acc2[rt][ct] = __builtin_amdgcn_mfma_f32_16x16x32_bf16(a2[rt], bw, acc2[rt][ct], 0, 0, 0);
                }
            }
            __syncthreads();           // all waves done reading actQ
        }
    }

    // ---- M3: residual + bias into st in-place (2x2 mapping; disjoint regions)
    #pragma unroll
    for (int ct = 0; ct < 3; ++ct) {
        const int col = wc * 48 + ct * 16 + lr;
        const float bias = b2[col];
        #pragma unroll
        for (int rt = 0; rt < 2; ++rt) {
            #pragma unroll
            for (int r = 0; r < 4; ++r) {
                const int row = wr * 32 + rt * 16 + lk * 4 + r;
                st[row * LDST + col] += acc2[rt][ct][r] + bias;
            }
        }
    }
    __syncthreads();

    // ---- P7: coalesced write-back; un-roll cancels the roll ----
    for (int i = tid; i < 64 * 96; i += 256) {
        int l = i / 96, c = i - l * 96;
        out[tbase[l] + c] = st[l * LDST + c];
    }
}

// ---------------------------------------------------------------------------
extern "C" void kernel_launch(void* const* d_in, const int* in_sizes, int n_in,
                              void* d_out, int out_size, void* d_ws, size_t ws_size,
                              hipStream_t stream) {
    const float* x    = (const float*)d_in[0];
    const float* ln1w = (const float*)d_in[1];
    const float* ln1b = (const float*)d_in[2];
    const float* wqkv = (const float*)d_in[3];   // [288,96]
    const float* bqkv = (const float*)d_in[4];
    const float* wo   = (const float*)d_in[5];   // [96,96]
    const float* bo   = (const float*)d_in[6];
    const float* ln2w = (const float*)d_in[7];
    const float* ln2b = (const float*)d_in[8];
    const float* w1   = (const float*)d_in[9];   // [384,96]
    const float* b1   = (const float*)d_in[10];
    const float* w2   = (const float*)d_in[11];  // [96,384]
    const float* b2   = (const float*)d_in[12];
    float* out = (float*)d_out;

    short* ws  = (short*)d_ws;
    short* wqb = ws;            // 27648
    short* wob = ws + 27648;    // 9216
    short* w1b = ws + 36864;    // 36864
    short* w2b = ws + 73728;    // 36864   (total 221184 B)

    prep_bf16<<<432, 256, 0, stream>>>(wqkv, wo, w1, w2, ws);
    attn_mlp<<<NW, 256, 0, stream>>>(x, ln1w, ln1b, wqb, bqkv, wob, bo,
                                     ln2w, ln2b, w1b, b1, w2b, b2, out);
}

// Round 6
// 190.987 us; speedup vs baseline: 1.7181x; 1.0016x over previous
//
#include <hip/hip_runtime.h>
#include <math.h>

// Problem constants (SwinBlock: B=4, H=W=224, C=96, WS=8, shift=4, NH=3, hd=32)
static constexpr int Hn   = 224;
static constexpr int Wn   = 224;
static constexpr int Cn   = 96;
static constexpr int Sft  = 4;     // WS/2
static constexpr int NWH  = 28;    // 224/8
static constexpr int NWPB = 784;   // 28*28
static constexpr int NW   = 3136;  // 4*784

typedef __attribute__((ext_vector_type(8))) short bf16x8;  // 8 bf16 in 4 VGPRs
typedef __attribute__((ext_vector_type(4))) float f32x4;
typedef __attribute__((ext_vector_type(4))) short s16x4;

__device__ inline short f2bf(float f) {            // RNE float->bf16
    unsigned u = __float_as_uint(f);
    return (short)((u + 0x7fffu + ((u >> 16) & 1u)) >> 16);
}

// Fast erf-based GELU (A&S 7.1.26, |eps_erf| <= 1.5e-7 -> invisible under the
// bf16 rounding that immediately follows).
__device__ inline float gelu_f(float a) {
    float u  = a * 0.70710678118654752f;
    float au = fabsf(u);
    float t  = __builtin_amdgcn_rcpf(fmaf(0.3275911f, au, 1.f));
    float e  = __expf(-u * u);
    float p  = t * fmaf(t, fmaf(t, fmaf(t, fmaf(t, 1.061405429f,
                        -1.453152027f), 1.421413741f), -0.284496736f),
                        0.254829592f);
    float er = fmaf(-p, e, 1.f);          // erf(|u|)
    er = (u < 0.f) ? -er : er;
    return 0.5f * a * (1.f + er);
}

// ---------------------------------------------------------------------------
// K0: convert ALL weights to bf16 into ws.
// layout (shorts): wqb[27648] | wob[9216] | w1b[36864] | w2b[36864]  (221184 B)
// ---------------------------------------------------------------------------
__global__ void prep_bf16(const float* __restrict__ wqkv, const float* __restrict__ wo,
                          const float* __restrict__ w1,   const float* __restrict__ w2,
                          short* __restrict__ ws) {
    int idx = blockIdx.x * 256 + threadIdx.x;
    if (idx < 27648)        ws[idx] = f2bf(wqkv[idx]);
    else if (idx < 36864)   ws[idx] = f2bf(wo[idx - 27648]);
    else if (idx < 73728)   ws[idx] = f2bf(w1[idx - 36864]);
    else if (idx < 110592)  ws[idx] = f2bf(w2[idx - 73728]);
}

// ---------------------------------------------------------------------------
// K1 (R6 == R3 exactly): fused attn+mlp, 3 blocks/CU.
//  - act buffer shrunk to a 96-col QUARTER (fits dead vt region) -> LDS
//    52992 B -> 3 blocks/CU.
//  - QKV GEMM (P3) and MLP GEMM2 use a 2x2 wave split (32 rows x half cols):
//    global B-loads per MFMA halved (1:1 -> 1:2).
// R4/R5's register-prefetch/packing additions REVERTED pending bisection
// (both failed absmax ~6e-3; this source passed at 191 us in round 3).
// Fragment layouts (mfma_f32_16x16x32_bf16, m89-verified):
//  A: row=lane&15, k=(lane>>4)*8+j ; B: col=lane&15, same k ;
//  D: col=lane&15, row=(lane>>4)*4+r
// LDS unions (time-shared):
//  U[25600]   : xf f32 -> Q|K bf16 -> P bf16 -> st f32 (lives to the end)
//  h2b[13312] : LN1-out -> O -> LN2-out
//  vtact[13824]: vt (V^T) -> actQ (GELU acts, one 96-col quarter)
// ---------------------------------------------------------------------------
static constexpr int LDH  = 104;  // h2b stride (shorts)
static constexpr int LDQK = 200;  // U as Q|K: stride (shorts): Q[0..95] K[96..191] pad8
static constexpr int LDVT = 72;   // vt stride (shorts): [ch 96][tok 64 pad8]
static constexpr int LDP  = 200;  // U as P: [tok][h*64+kv] pad8 (shorts)
static constexpr int LDXF = 100;  // U as xf: stride (floats)
static constexpr int LDST = 100;  // U as st: stride (floats)
static constexpr int LDAQ = 104;  // actQ stride (shorts), one 96-col quarter

__global__ __launch_bounds__(256, 3) void attn_mlp(
    const float* __restrict__ x,
    const float* __restrict__ ln1w, const float* __restrict__ ln1b,
    const short* __restrict__ wqb,  const float* __restrict__ bqkv,
    const short* __restrict__ wob,  const float* __restrict__ bo,
    const float* __restrict__ ln2w, const float* __restrict__ ln2b,
    const short* __restrict__ w1b,  const float* __restrict__ b1,
    const short* __restrict__ w2b,  const float* __restrict__ b2,
    float* __restrict__ out)
{
    __shared__ __align__(16) char  U[64 * 400];        // xf -> Q|K -> P -> st
    __shared__ __align__(16) short h2b[64 * LDH];      // LN1 -> O -> LN2
    __shared__ __align__(16) short vtact[96 * LDVT];   // vt -> actQ (64*LDAQ fits)
    __shared__ int   tbase[64];

    const int blk = blockIdx.x;
    const int b   = blk / NWPB;
    const int rem = blk - b * NWPB;
    const int wh  = rem / NWH;
    const int ww  = rem - wh * NWH;
    const int tid  = threadIdx.x;
    const int lane = tid & 63;
    const int wv   = __builtin_amdgcn_readfirstlane(tid >> 6);
    const int lr   = lane & 15;
    const int lk   = lane >> 4;
    const int wr   = wv >> 1;   // 2x2 wave split: row group (32 rows)
    const int wc   = wv & 1;    //                 col group

    if (tid < 64) {
        int i = tid >> 3, j = tid & 7;
        int hs = wh * 8 + i + Sft; if (hs >= Hn) hs -= Hn;
        int ws2 = ww * 8 + j + Sft; if (ws2 >= Wn) ws2 -= Wn;
        tbase[tid] = ((b * Hn + hs) * Wn + ws2) * Cn;
    }
    __syncthreads();

    // ---- P1: load x [64][96] (float4, 16B-aligned rows) into U as xf ----
    float* xf = (float*)U;
    for (int i = tid; i < 64 * 24; i += 256) {
        int row = i / 24, c4 = i - row * 24;
        float4 v = ((const float4*)(x + tbase[row]))[c4];
        *(float4*)&xf[row * LDXF + c4 * 4] = v;
    }
    __syncthreads();

    // ---- P2: LN1 (4 lanes/token) ----
    {
        const int l = tid >> 2, p = tid & 3;
        float s0 = 0.f, s1 = 0.f;
        #pragma unroll
        for (int c0 = 0; c0 < 24; ++c0) {
            float v = xf[l * LDXF + p * 24 + c0];
            s0 += v; s1 += v * v;
        }
        s0 += __shfl_xor(s0, 1); s1 += __shfl_xor(s1, 1);
        s0 += __shfl_xor(s0, 2); s1 += __shfl_xor(s1, 2);
        float mean = s0 * (1.f / 96.f);
        float var  = fmaxf(s1 * (1.f / 96.f) - mean * mean, 0.f);
        float rstd = rsqrtf(var + 1e-5f);
        #pragma unroll
        for (int c0 = 0; c0 < 24; ++c0) {
            int c = p * 24 + c0;
            float v = xf[l * LDXF + c];
            h2b[l * LDH + c] = f2bf((v - mean) * rstd * ln1w[c] + ln1b[c]);
        }
    }
    __syncthreads();   // h2b ready; xf dead (fences Q/K overwrite)

    // ---- P3: QKV GEMM, 2x2 split: rows wr*32 (2 rt), col-tiles wc*9..wc*9+8 ----
    short* qk = (short*)U;
    short* vt = vtact;
    {
        bf16x8 aq[2][3];
        #pragma unroll
        for (int rt = 0; rt < 2; ++rt)
            #pragma unroll
            for (int ks = 0; ks < 3; ++ks)
                aq[rt][ks] = *(const bf16x8*)&h2b[(wr * 32 + rt * 16 + lr) * LDH + ks * 32 + lk * 8];

        #pragma unroll 3
        for (int ct9 = 0; ct9 < 9; ++ct9) {
            const int ct = wc * 9 + ct9;
            const short* bp = wqb + (ct * 16 + lr) * 96 + lk * 8;
            bf16x8 b0 = *(const bf16x8*)(bp);
            bf16x8 b1 = *(const bf16x8*)(bp + 32);
            bf16x8 b2 = *(const bf16x8*)(bp + 64);
            const int col  = ct * 16 + lr;
            const float bs = bqkv[col];                // L2-hot global
            #pragma unroll
            for (int rt = 0; rt < 2; ++rt) {
                f32x4 acc = (f32x4){0.f, 0.f, 0.f, 0.f};
                acc = __builtin_amdgcn_mfma_f32_16x16x32_bf16(aq[rt][0], b0, acc, 0, 0, 0);
                acc = __builtin_amdgcn_mfma_f32_16x16x32_bf16(aq[rt][1], b1, acc, 0, 0, 0);
                acc = __builtin_amdgcn_mfma_f32_16x16x32_bf16(aq[rt][2], b2, acc, 0, 0, 0);
                const int rb = wr * 32 + rt * 16;
                if (ct < 12) {            // Q,K -> [tok][ch] in U
                    #pragma unroll
                    for (int r = 0; r < 4; ++r)
                        qk[(rb + lk * 4 + r) * LDQK + col] = f2bf(acc[r] + bs);
                } else {                  // V -> transposed [ch][tok], packed b64
                    s16x4 pk;
                    #pragma unroll
                    for (int r = 0; r < 4; ++r) pk[r] = f2bf(acc[r] + bs);
                    *(s16x4*)&vt[(col - 192) * LDVT + rb + lk * 4] = pk;
                }
            }
        }
    }
    __syncthreads();   // Q,K,V visible to all waves

    // ---- P4: S = QK^T per head (wave -> query row-tile wv), softmax ----
    short* pb = (short*)U;   // P overwrites Q|K after the barrier below
    {
        f32x4 accs[3][4];
        #pragma unroll
        for (int h = 0; h < 3; ++h) {
            bf16x8 aqf = *(const bf16x8*)&qk[(wv * 16 + lr) * LDQK + h * 32 + lk * 8];
            #pragma unroll
            for (int ct = 0; ct < 4; ++ct) {
                bf16x8 bk = *(const bf16x8*)&qk[(ct * 16 + lr) * LDQK + 96 + h * 32 + lk * 8];
                f32x4 z = (f32x4){0.f, 0.f, 0.f, 0.f};
                accs[h][ct] = __builtin_amdgcn_mfma_f32_16x16x32_bf16(aqf, bk, z, 0, 0, 0);
            }
        }
        __syncthreads();   // every wave done reading K -> P may overwrite U

        const float scale = 0.17677669529663687f;  // 1/sqrt(32)
        float inv[3][4];
        #pragma unroll
        for (int h = 0; h < 3; ++h) {
            #pragma unroll
            for (int r = 0; r < 4; ++r) {
                float m = fmaxf(fmaxf(accs[h][0][r], accs[h][1][r]),
                                fmaxf(accs[h][2][r], accs[h][3][r]));
                m = fmaxf(m, __shfl_xor(m, 1));
                m = fmaxf(m, __shfl_xor(m, 2));
                m = fmaxf(m, __shfl_xor(m, 4));
                m = fmaxf(m, __shfl_xor(m, 8));
                float s = 0.f;
                #pragma unroll
                for (int ct = 0; ct < 4; ++ct) {
                    float p = __expf((accs[h][ct][r] - m) * scale);
                    accs[h][ct][r] = p; s += p;
                }
                s += __shfl_xor(s, 1); s += __shfl_xor(s, 2);
                s += __shfl_xor(s, 4); s += __shfl_xor(s, 8);
                inv[h][r] = 1.f / s;
            }
        }
        // P -> bf16 LDS (rows of own wave only; no barrier needed)
        #pragma unroll
        for (int h = 0; h < 3; ++h)
            #pragma unroll
            for (int ct = 0; ct < 4; ++ct)
                #pragma unroll
                for (int r = 0; r < 4; ++r)
                    pb[(wv * 16 + lk * 4 + r) * LDP + h * 64 + ct * 16 + lr] =
                        f2bf(accs[h][ct][r]);

        // ---- P5: O = P V (deferred 1/sum), write O bf16 into h2b ----
        f32x4 acco[3][2];
        #pragma unroll
        for (int h = 0; h < 3; ++h)
            #pragma unroll
            for (int ct = 0; ct < 2; ++ct) acco[h][ct] = (f32x4){0.f, 0.f, 0.f, 0.f};
        #pragma unroll
        for (int h = 0; h < 3; ++h) {
            #pragma unroll
            for (int ks = 0; ks < 2; ++ks) {
                bf16x8 ap = *(const bf16x8*)&pb[(wv * 16 + lr) * LDP + h * 64 + ks * 32 + lk * 8];
                #pragma unroll
                for (int ct = 0; ct < 2; ++ct) {
                    bf16x8 bv = *(const bf16x8*)&vt[(h * 32 + ct * 16 + lr) * LDVT + ks * 32 + lk * 8];
                    acco[h][ct] = __builtin_amdgcn_mfma_f32_16x16x32_bf16(ap, bv, acco[h][ct], 0, 0, 0);
                }
            }
        }
        #pragma unroll
        for (int h = 0; h < 3; ++h)
            #pragma unroll
            for (int ct = 0; ct < 2; ++ct)
                #pragma unroll
                for (int r = 0; r < 4; ++r)
                    h2b[(wv * 16 + lk * 4 + r) * LDH + h * 32 + ct * 16 + lr] =
                        f2bf(acco[h][ct][r] * inv[h][r]);
    }

    // ---- P6: out-proj -> st f32 (own-wave 16 rows; keeps barrier-free LN2) ----
    float* st = (float*)U;   // overwrites pb: own-wave rows, program-ordered
    {
        bf16x8 o0 = *(const bf16x8*)&h2b[(wv * 16 + lr) * LDH +  0 + lk * 8];
        bf16x8 o1 = *(const bf16x8*)&h2b[(wv * 16 + lr) * LDH + 32 + lk * 8];
        bf16x8 o2 = *(const bf16x8*)&h2b[(wv * 16 + lr) * LDH + 64 + lk * 8];
        #pragma unroll
        for (int ct = 0; ct < 6; ++ct) {
            const short* bp = wob + (ct * 16 + lr) * 96 + lk * 8;
            bf16x8 b0 = *(const bf16x8*)(bp);
            bf16x8 b1 = *(const bf16x8*)(bp + 32);
            bf16x8 b2 = *(const bf16x8*)(bp + 64);
            f32x4 acc = (f32x4){0.f, 0.f, 0.f, 0.f};
            acc = __builtin_amdgcn_mfma_f32_16x16x32_bf16(o0, b0, acc, 0, 0, 0);
            acc = __builtin_amdgcn_mfma_f32_16x16x32_bf16(o1, b1, acc, 0, 0, 0);
            acc = __builtin_amdgcn_mfma_f32_16x16x32_bf16(o2, b2, acc, 0, 0, 0);
            const int col = ct * 16 + lr;
            const float bs = bo[col];                  // L2-hot global
            #pragma unroll
            for (int r = 0; r < 4; ++r)
                st[(wv * 16 + lk * 4 + r) * LDST + col] = acc[r] + bs;
        }
    }
    // No barrier: LN2 reads st rows [wv*16, wv*16+16) = own-wave rows.

    // ---- M1: LN2 from st (LDS), write h2b (own-wave rows) ----
    {
        const int l = tid >> 2, p = tid & 3;
        float s0 = 0.f, s1 = 0.f;
        #pragma unroll
        for (int c0 = 0; c0 < 24; ++c0) {
            float v = st[l * LDST + p * 24 + c0];
            s0 += v; s1 += v * v;
        }
        s0 += __shfl_xor(s0, 1); s1 += __shfl_xor(s1, 1);
        s0 += __shfl_xor(s0, 2); s1 += __shfl_xor(s1, 2);
        float mean = s0 * (1.f / 96.f);
        float var  = fmaxf(s1 * (1.f / 96.f) - mean * mean, 0.f);
        float rstd = rsqrtf(var + 1e-5f);
        #pragma unroll
        for (int c0 = 0; c0 < 24; ++c0) {
            int c = p * 24 + c0;
            float v = st[l * LDST + c];
            h2b[l * LDH + c] = f2bf((v - mean) * rstd * ln2w[c] + ln2b[c]);
        }
    }
    __syncthreads();   // h2b(LN2) + st complete; vt dead beyond here

    // ---- M2: MLP. GEMM1 per half (192 cols, wave=48 cols x 64 rows, 1:4);
    //      act stored per 96-col QUARTER in actQ; GEMM2 per quarter with 2x2
    //      split (32 rows x 48 cols, 1:2). ----
    short* actQ = vtact;
    bf16x8 a1[4][3];
    #pragma unroll
    for (int rt = 0; rt < 4; ++rt)
        #pragma unroll
        for (int ks = 0; ks < 3; ++ks)
            a1[rt][ks] = *(const bf16x8*)&h2b[(rt * 16 + lr) * LDH + ks * 32 + lk * 8];

    f32x4 acc2[2][3];   // rows wr*32+rt*16, cols wc*48+ct*16
    #pragma unroll
    for (int rt = 0; rt < 2; ++rt)
        #pragma unroll
        for (int ct = 0; ct < 3; ++ct) acc2[rt][ct] = (f32x4){0.f, 0.f, 0.f, 0.f};

    for (int half = 0; half < 2; ++half) {
        const int oc0w = half * 192 + wv * 48;
        f32x4 acc1[4][3];
        #pragma unroll
        for (int rt = 0; rt < 4; ++rt)
            #pragma unroll
            for (int ct = 0; ct < 3; ++ct) acc1[rt][ct] = (f32x4){0.f, 0.f, 0.f, 0.f};

        #pragma unroll
        for (int ct = 0; ct < 3; ++ct) {
            const short* bp = w1b + (oc0w + ct * 16 + lr) * 96 + lk * 8;
            bf16x8 bg0 = *(const bf16x8*)(bp);
            bf16x8 bg1 = *(const bf16x8*)(bp + 32);
            bf16x8 bg2 = *(const bf16x8*)(bp + 64);
            #pragma unroll
            for (int rt = 0; rt < 4; ++rt) {
                acc1[rt][ct] = __builtin_amdgcn_mfma_f32_16x16x32_bf16(a1[rt][0], bg0, acc1[rt][ct], 0, 0, 0);
                acc1[rt][ct] = __builtin_amdgcn_mfma_f32_16x16x32_bf16(a1[rt][1], bg1, acc1[rt][ct], 0, 0, 0);
                acc1[rt][ct] = __builtin_amdgcn_mfma_f32_16x16x32_bf16(a1[rt][2], bg2, acc1[rt][ct], 0, 0, 0);
            }
        }

        for (int sub = 0; sub < 2; ++sub) {
            // waves whose 48 cols fall in quarter `sub` write act (bias+GELU)
            if (wr == sub) {
                #pragma unroll
                for (int ct = 0; ct < 3; ++ct) {
                    float bias = b1[oc0w + ct * 16 + lr];
                    const int lcol = wc * 48 + ct * 16 + lr;   // col within quarter
                    #pragma unroll
                    for (int rt = 0; rt < 4; ++rt) {
                        #pragma unroll
                        for (int r = 0; r < 4; ++r) {
                            float g = gelu_f(acc1[rt][ct][r] + bias);
                            actQ[(rt * 16 + lk * 4 + r) * LDAQ + lcol] = f2bf(g);
                        }
                    }
                }
            }
            __syncthreads();           // actQ(quarter) ready

            // GEMM2 slice: k = half*192 + sub*96 .. +96
            #pragma unroll
            for (int ks = 0; ks < 3; ++ks) {
                bf16x8 a2[2];
                #pragma unroll
                for (int rt = 0; rt < 2; ++rt)
                    a2[rt] = *(const bf16x8*)&actQ[(wr * 32 + rt * 16 + lr) * LDAQ + ks * 32 + lk * 8];
                #pragma unroll
                for (int ct = 0; ct < 3; ++ct) {
                    bf16x8 bw = *(const bf16x8*)(w2b + (wc * 48 + ct * 16 + lr) * 384
                                                  + half * 192 + sub * 96 + ks * 32 + lk * 8);
                    #pragma unroll
                    for (int rt = 0; rt < 2; ++rt)
                        acc2[rt][ct] = __builtin_amdgcn_mfma_f32_16x16x32_bf16(a2[rt], bw, acc2[rt][ct], 0, 0, 0);
                }
            }
            __syncthreads();           // all waves done reading actQ
        }
    }

    // ---- M3: residual + bias into st in-place (2x2 mapping; disjoint regions)
    #pragma unroll
    for (int ct = 0; ct < 3; ++ct) {
        const int col = wc * 48 + ct * 16 + lr;
        const float bias = b2[col];
        #pragma unroll
        for (int rt = 0; rt < 2; ++rt) {
            #pragma unroll
            for (int r = 0; r < 4; ++r) {
                const int row = wr * 32 + rt * 16 + lk * 4 + r;
                st[row * LDST + col] += acc2[rt][ct][r] + bias;
            }
        }
    }
    __syncthreads();

    // ---- P7: coalesced write-back; un-roll cancels the roll ----
    for (int i = tid; i < 64 * 96; i += 256) {
        int l = i / 96, c = i - l * 96;
        out[tbase[l] + c] = st[l * LDST + c];
    }
}

// ---------------------------------------------------------------------------
extern "C" void kernel_launch(void* const* d_in, const int* in_sizes, int n_in,
                              void* d_out, int out_size, void* d_ws, size_t ws_size,
                              hipStream_t stream) {
    const float* x    = (const float*)d_in[0];
    const float* ln1w = (const float*)d_in[1];
    const float* ln1b = (const float*)d_in[2];
    const float* wqkv = (const float*)d_in[3];   // [288,96]
    const float* bqkv = (const float*)d_in[4];
    const float* wo   = (const float*)d_in[5];   // [96,96]
    const float* bo   = (const float*)d_in[6];
    const float* ln2w = (const float*)d_in[7];
    const float* ln2b = (const float*)d_in[8];
    const float* w1   = (const float*)d_in[9];   // [384,96]
    const float* b1   = (const float*)d_in[10];
    const float* w2   = (const float*)d_in[11];  // [96,384]
    const float* b2   = (const float*)d_in[12];
    float* out = (float*)d_out;

    short* ws  = (short*)d_ws;
    short* wqb = ws;            // 27648
    short* wob = ws + 27648;    // 9216
    short* w1b = ws + 36864;    // 36864
    short* w2b = ws + 73728;    // 36864   (total 221184 B)

    prep_bf16<<<432, 256, 0, stream>>>(wqkv, wo, w1, w2, ws);
    attn_mlp<<<NW, 256, 0, stream>>>(x, ln1w, ln1b, wqb, bqkv, wob, bo,
                                     ln2w, ln2b, w1b, b1, w2b, b2, out);
}